// Round 1
// baseline (164.864 us; speedup 1.0000x reference)
//
#include <hip/hip_runtime.h>
#include <cstdint>

#define B_SZ   16384
#define H_SZ   512
#define DIN    256
#define TEMB   16
#define KP     1344          // packed K: x[0,256) h[256,768) c[768,1280) delt[1280,1296) pad[1296,1344)
#define NKB    21            // 21 K-blocks of 64
#define BH     8388608L      // B_SZ*H_SZ

typedef __attribute__((ext_vector_type(4))) float f32x4;
typedef __bf16 bf16x8 __attribute__((ext_vector_type(8)));

typedef const __attribute__((address_space(1))) unsigned int gu32_t;
typedef __attribute__((address_space(3)))       unsigned int lu32_t;

__device__ __forceinline__ void gld16(const void* g, void* l) {
  // global -> LDS direct copy, 16B per lane. LDS dest must be wave-uniform base (+lane*16).
  __builtin_amdgcn_global_load_lds((gu32_t*)(uintptr_t)g,
                                   (lu32_t*)(unsigned int)(uintptr_t)l, 16, 0, 0);
}

__device__ __forceinline__ unsigned short f2bf(float f) {
  unsigned int u = __float_as_uint(f);
  u += 0x7FFFu + ((u >> 16) & 1u);   // RNE; inputs finite
  return (unsigned short)(u >> 16);
}

__device__ __forceinline__ float sigm(float v)  { return 1.0f / (1.0f + __expf(-v)); }
__device__ __forceinline__ float tanhx(float v) { return 2.0f / (1.0f + __expf(-2.0f * v)) - 1.0f; }

// ---------------- prep: pack A = [x|h|c|delt|0] as bf16 [B][KP] ----------------
__global__ void prep_a_kernel(const float* __restrict__ x, const float* __restrict__ h,
                              const float* __restrict__ c, const float* __restrict__ dl,
                              unsigned short* __restrict__ Ap) {
  long idx = (long)blockIdx.x * 256 + threadIdx.x;      // one float4 per thread
  const long n4 = (long)B_SZ * KP / 4;
  if (idx >= n4) return;
  int row = (int)(idx / (KP / 4));
  int k4  = (int)(idx % (KP / 4)) * 4;
  float4 v = make_float4(0.f, 0.f, 0.f, 0.f);
  if (k4 < 256)       v = *(const float4*)(x  + (long)row * DIN  + k4);
  else if (k4 < 768)  v = *(const float4*)(h  + (long)row * H_SZ + (k4 - 256));
  else if (k4 < 1280) v = *(const float4*)(c  + (long)row * H_SZ + (k4 - 768));
  else if (k4 < 1296) v = *(const float4*)(dl + (long)row * TEMB + (k4 - 1280));
  ushort4 o;
  o.x = f2bf(v.x); o.y = f2bf(v.y); o.z = f2bf(v.z); o.w = f2bf(v.w);
  *(ushort4*)(Ap + idx * 4) = o;
}

// ---------------- prep: pack Wp[6][512][KP] bf16 (gate-segment layout matches A) ----------------
__global__ void prep_w_kernel(const float* __restrict__ Wix, const float* __restrict__ Wih, const float* __restrict__ Wic,
                              const float* __restrict__ Wfx, const float* __restrict__ Wfh, const float* __restrict__ Wfc,
                              const float* __restrict__ Wtx, const float* __restrict__ Wtt,
                              const float* __restrict__ Wcx, const float* __restrict__ Wch,
                              const float* __restrict__ Wox, const float* __restrict__ Woh,
                              const float* __restrict__ Woc, const float* __restrict__ Wot,
                              unsigned short* __restrict__ Wp) {
  long idx = (long)blockIdx.x * 256 + threadIdx.x;
  const long n4 = 6L * H_SZ * KP / 4;
  if (idx >= n4) return;
  int k4   = (int)(idx % (KP / 4)) * 4;
  int rest = (int)(idx / (KP / 4));
  int n = rest & 511;
  int g = rest >> 9;
  const float* src = nullptr; long o = 0;
  if (g == 0) {            // i: x,h,c
    if (k4 < 256)       { src = Wix; o = (long)n * 256 + k4; }
    else if (k4 < 768)  { src = Wih; o = (long)n * 512 + (k4 - 256); }
    else if (k4 < 1280) { src = Wic; o = (long)n * 512 + (k4 - 768); }
  } else if (g == 1) {     // f: x,h,c
    if (k4 < 256)       { src = Wfx; o = (long)n * 256 + k4; }
    else if (k4 < 768)  { src = Wfh; o = (long)n * 512 + (k4 - 256); }
    else if (k4 < 1280) { src = Wfc; o = (long)n * 512 + (k4 - 768); }
  } else if (g == 2) {     // t: x only
    if (k4 < 256)       { src = Wtx; o = (long)n * 256 + k4; }
  } else if (g == 3) {     // k: x,h
    if (k4 < 256)       { src = Wcx; o = (long)n * 256 + k4; }
    else if (k4 < 768)  { src = Wch; o = (long)n * 512 + (k4 - 256); }
  } else if (g == 4) {     // o: x,h,c,delt
    if (k4 < 256)       { src = Wox; o = (long)n * 256 + k4; }
    else if (k4 < 768)  { src = Woh; o = (long)n * 512 + (k4 - 256); }
    else if (k4 < 1280) { src = Woc; o = (long)n * 512 + (k4 - 768); }
    else if (k4 < 1296) { src = Wot; o = (long)n * 16 + (k4 - 1280); }
  } else {                 // t_inner: delt only
    if (k4 >= 1280 && k4 < 1296) { src = Wtt; o = (long)n * 16 + (k4 - 1280); }
  }
  float4 v = make_float4(0.f, 0.f, 0.f, 0.f);
  if (src) v = *(const float4*)(src + o);
  ushort4 u;
  u.x = f2bf(v.x); u.y = f2bf(v.y); u.z = f2bf(v.z); u.w = f2bf(v.w);
  *(ushort4*)(Wp + idx * 4) = u;
}

// swizzled LDS frag read: byte = r*128 + ((koff*2) ^ ((r&7)<<4))
#define LDS_FRAG(baseoff, r, koff) \
  (*(const bf16x8*)(lds + (baseoff) + (r) * 128 + (((koff) * 2) ^ (((r) & 7) << 4))))

// ---------------- main fused kernel ----------------
__global__ __launch_bounds__(256) void lstm_main(
    const unsigned short* __restrict__ Ap, const unsigned short* __restrict__ Wp,
    const float* __restrict__ c_prev,
    const float* __restrict__ b_ix, const float* __restrict__ b_fx,
    const float* __restrict__ b_tx, const float* __restrict__ b_cx,
    const float* __restrict__ b_ox,
    float* __restrict__ out)
{
  __shared__ f32x4 lds_[6 * 8192 / 16];     // A-buf + 5 W-buf slots, 8 KB each
  char* lds = (char*)lds_;

  const int tid  = threadIdx.x;
  const int lane = tid & 63;
  const int wid  = tid >> 6;

  // bijective XCD swizzle: 2048 wgs, each XCD gets one full weight-column block
  const int bid = blockIdx.x;
  const int swz = (bid & 7) * 256 + (bid >> 3);
  const int bx  = swz & 255;                 // row block (0..255)
  const int by  = swz >> 8;                  // col block (0..7)
  const unsigned brow = (unsigned)bx * 64u;
  const int bcol = by * 64;

  const int wr = (wid >> 1) * 32;            // wave tile origin (2x2 waves of 32x32)
  const int wc = (wid & 1) * 32;

  constexpr int slotc[6] = {0, 1, 2, 3, 4, 2};  // gate->W slot (gate5 reuses slot2: disjoint masks)

  f32x4 acc[6][2][2];
  {
    f32x4 z = {0.f, 0.f, 0.f, 0.f};
#pragma unroll
    for (int g = 0; g < 6; ++g)
#pragma unroll
      for (int a = 0; a < 2; ++a)
#pragma unroll
        for (int b = 0; b < 2; ++b) acc[g][a][b] = z;
  }

  // staging coords: chunk cidx = j*256+tid; row = cidx>>3 (j=1 -> +32), ch = cidx&7
  const int row0 = tid >> 3;
  const int ch0  = tid & 7;
  const int sb0  = (ch0 * 16) ^ ((row0 & 7) << 4);   // pre-swizzled source offset (row+32 identical)

  const unsigned aoff    = (brow + (unsigned)row0) * (KP * 2u) + (unsigned)sb0;
  const unsigned woff    = ((unsigned)(bcol + row0)) * (KP * 2u) + (unsigned)sb0;
  const unsigned rowskip = 32u * (KP * 2u);
  const unsigned gstride = (unsigned)H_SZ * (KP * 2u);

  const int ldst = wid * 1024;               // wave-uniform LDS dest base
  const char* apc = (const char*)Ap;
  const char* wpc = (const char*)Wp;

  const int lrow = lane & 15;
  const int kgrp = lane >> 4;

#pragma unroll 1
  for (int kb = 0; kb < NKB; ++kb) {
    const unsigned mask = (kb < 4) ? 0x1Fu : (kb < 12) ? 0x1Bu : (kb < 20) ? 0x13u : 0x30u;
    const unsigned kbyte = (unsigned)kb * 128u;

    // stage A tile (64 rows x 128 B)
    gld16(apc + (aoff + kbyte),           lds + ldst);
    gld16(apc + (aoff + rowskip + kbyte), lds + 4096 + ldst);

    // stage active W tiles
#pragma unroll
    for (int g = 0; g < 6; ++g) {
      if (mask & (1u << g)) {
        const int sbase = (slotc[g] + 1) * 8192 + ldst;
        const unsigned wsrc = woff + (unsigned)g * gstride + kbyte;
        gld16(wpc + wsrc,             lds + sbase);
        gld16(wpc + (wsrc + rowskip), lds + sbase + 4096);
      }
    }

    __syncthreads();   // drains vmcnt before any wave reads LDS

#pragma unroll
    for (int kf = 0; kf < 2; ++kf) {
      const int koff = kf * 32 + kgrp * 8;
      const int ar0 = wr + lrow;
      const int ar1 = ar0 + 16;
      bf16x8 a0 = LDS_FRAG(0, ar0, koff);
      bf16x8 a1 = LDS_FRAG(0, ar1, koff);
#pragma unroll
      for (int g = 0; g < 6; ++g) {
        if (mask & (1u << g)) {
          const int wbase = (slotc[g] + 1) * 8192;
          const int nr0 = wc + lrow;
          const int nr1 = nr0 + 16;
          bf16x8 b0 = LDS_FRAG(wbase, nr0, koff);
          bf16x8 b1 = LDS_FRAG(wbase, nr1, koff);
          acc[g][0][0] = __builtin_amdgcn_mfma_f32_16x16x32_bf16(a0, b0, acc[g][0][0], 0, 0, 0);
          acc[g][1][0] = __builtin_amdgcn_mfma_f32_16x16x32_bf16(a1, b0, acc[g][1][0], 0, 0, 0);
          acc[g][0][1] = __builtin_amdgcn_mfma_f32_16x16x32_bf16(a0, b1, acc[g][0][1], 0, 0, 0);
          acc[g][1][1] = __builtin_amdgcn_mfma_f32_16x16x32_bf16(a1, b1, acc[g][1][1], 0, 0, 0);
        }
      }
    }
    __syncthreads();
  }

  // ---------------- fused epilogue ----------------
  const int rbase = kgrp * 4;
#pragma unroll
  for (int rf = 0; rf < 2; ++rf) {
#pragma unroll
    for (int cf = 0; cf < 2; ++cf) {
      const int n = bcol + wc + cf * 16 + lrow;
      const float bi = b_ix[n], bff = b_fx[n], bt = b_tx[n], bc = b_cx[n], bo = b_ox[n];
#pragma unroll
      for (int r = 0; r < 4; ++r) {
        const long m   = (long)brow + wr + rf * 16 + rbase + r;
        const long off = m * H_SZ + n;
        const float iv = sigm(acc[0][rf][cf][r] + bi);
        const float fv = sigm(acc[1][rf][cf][r] + bff);
        const float Tv = sigm(acc[2][rf][cf][r] + bt + sigm(acc[5][rf][cf][r]));
        const float kv = tanhx(acc[3][rf][cf][r] + bc);
        const float ov = sigm(acc[4][rf][cf][r] + bo);
        const float cp = c_prev[off];
        const float cn = iv * Tv * kv + fv * cp;
        out[off]          = ov * tanhx(cn);
        out[BH + off]     = cn;
        out[2 * BH + off] = Tv;
      }
    }
  }
}

extern "C" void kernel_launch(void* const* d_in, const int* in_sizes, int n_in,
                              void* d_out, int out_size, void* d_ws, size_t ws_size,
                              hipStream_t stream) {
  const float* x      = (const float*)d_in[0];
  const float* h      = (const float*)d_in[1];
  const float* c_prev = (const float*)d_in[2];
  const float* dl     = (const float*)d_in[3];
  const float* W_ix = (const float*)d_in[4];
  const float* b_ix = (const float*)d_in[5];
  const float* W_ih = (const float*)d_in[6];
  const float* W_ic = (const float*)d_in[7];
  const float* W_fx = (const float*)d_in[8];
  const float* b_fx = (const float*)d_in[9];
  const float* W_fh = (const float*)d_in[10];
  const float* W_fc = (const float*)d_in[11];
  const float* W_tx = (const float*)d_in[12];
  const float* b_tx = (const float*)d_in[13];
  const float* W_tt = (const float*)d_in[14];
  const float* W_cx = (const float*)d_in[15];
  const float* b_cx = (const float*)d_in[16];
  const float* W_ch = (const float*)d_in[17];
  const float* W_ox = (const float*)d_in[18];
  const float* b_ox = (const float*)d_in[19];
  const float* W_oh = (const float*)d_in[20];
  const float* W_oc = (const float*)d_in[21];
  const float* W_ot = (const float*)d_in[22];

  unsigned short* Ap = (unsigned short*)d_ws;                                   // 44.04 MB
  unsigned short* Wp = (unsigned short*)((char*)d_ws + (size_t)B_SZ * KP * 2);  // +8.26 MB

  const long na4 = (long)B_SZ * KP / 4;
  prep_a_kernel<<<(int)((na4 + 255) / 256), 256, 0, stream>>>(x, h, c_prev, dl, Ap);
  const long nw4 = 6L * H_SZ * KP / 4;
  prep_w_kernel<<<(int)((nw4 + 255) / 256), 256, 0, stream>>>(
      W_ix, W_ih, W_ic, W_fx, W_fh, W_fc, W_tx, W_tt, W_cx, W_ch,
      W_ox, W_oh, W_oc, W_ot, Wp);

  lstm_main<<<2048, 256, 0, stream>>>(Ap, Wp, c_prev, b_ix, b_fx, b_tx, b_cx, b_ox,
                                      (float*)d_out);
}

// Round 2
// 159.666 us; speedup vs baseline: 1.0326x; 1.0326x over previous
//
#include <hip/hip_runtime.h>
#include <cstdint>

#define B_SZ   16384
#define H_SZ   512
#define DIN    256
#define TEMB   16
#define KP     1344          // packed K: x[0,256) h[256,768) c[768,1280) delt[1280,1296) pad[1296,1344)
#define KPB    2688          // KP*2 bytes per row
#define NKB    21            // 21 K-blocks of 64
#define BH     8388608L      // B_SZ*H_SZ
#define BUFSZ  40960         // per-buffer LDS bytes: A 16K + W 6*4K
#define WOFF   16384         // W region offset inside buffer

typedef __attribute__((ext_vector_type(4))) float f32x4;
typedef __bf16 bf16x8 __attribute__((ext_vector_type(8)));

typedef const __attribute__((address_space(1))) unsigned int gu32_t;
typedef __attribute__((address_space(3)))       unsigned int lu32_t;

__device__ __forceinline__ void gld16(const void* g, void* l) {
  __builtin_amdgcn_global_load_lds((gu32_t*)(uintptr_t)g,
                                   (lu32_t*)(unsigned int)(uintptr_t)l, 16, 0, 0);
}

__device__ __forceinline__ unsigned short f2bf(float f) {
  unsigned int u = __float_as_uint(f);
  u += 0x7FFFu + ((u >> 16) & 1u);   // RNE; inputs finite
  return (unsigned short)(u >> 16);
}

__device__ __forceinline__ float sigm(float v)  { return 1.0f / (1.0f + __expf(-v)); }
__device__ __forceinline__ float tanhx(float v) { return 2.0f / (1.0f + __expf(-2.0f * v)) - 1.0f; }

// ---------------- prep: pack A = [x|h|c|delt|0] as bf16 [B][KP] ----------------
__global__ void prep_a_kernel(const float* __restrict__ x, const float* __restrict__ h,
                              const float* __restrict__ c, const float* __restrict__ dl,
                              unsigned short* __restrict__ Ap) {
  long idx = (long)blockIdx.x * 256 + threadIdx.x;
  const long n4 = (long)B_SZ * KP / 4;
  if (idx >= n4) return;
  int row = (int)(idx / (KP / 4));
  int k4  = (int)(idx % (KP / 4)) * 4;
  float4 v = make_float4(0.f, 0.f, 0.f, 0.f);
  if (k4 < 256)       v = *(const float4*)(x  + (long)row * DIN  + k4);
  else if (k4 < 768)  v = *(const float4*)(h  + (long)row * H_SZ + (k4 - 256));
  else if (k4 < 1280) v = *(const float4*)(c  + (long)row * H_SZ + (k4 - 768));
  else if (k4 < 1296) v = *(const float4*)(dl + (long)row * TEMB + (k4 - 1280));
  ushort4 o;
  o.x = f2bf(v.x); o.y = f2bf(v.y); o.z = f2bf(v.z); o.w = f2bf(v.w);
  *(ushort4*)(Ap + idx * 4) = o;
}

// ---------------- prep: pack Wp[6][512][KP] bf16 ----------------
__global__ void prep_w_kernel(const float* __restrict__ Wix, const float* __restrict__ Wih, const float* __restrict__ Wic,
                              const float* __restrict__ Wfx, const float* __restrict__ Wfh, const float* __restrict__ Wfc,
                              const float* __restrict__ Wtx, const float* __restrict__ Wtt,
                              const float* __restrict__ Wcx, const float* __restrict__ Wch,
                              const float* __restrict__ Wox, const float* __restrict__ Woh,
                              const float* __restrict__ Woc, const float* __restrict__ Wot,
                              unsigned short* __restrict__ Wp) {
  long idx = (long)blockIdx.x * 256 + threadIdx.x;
  const long n4 = 6L * H_SZ * KP / 4;
  if (idx >= n4) return;
  int k4   = (int)(idx % (KP / 4)) * 4;
  int rest = (int)(idx / (KP / 4));
  int n = rest & 511;
  int g = rest >> 9;
  const float* src = nullptr; long o = 0;
  if (g == 0) {
    if (k4 < 256)       { src = Wix; o = (long)n * 256 + k4; }
    else if (k4 < 768)  { src = Wih; o = (long)n * 512 + (k4 - 256); }
    else if (k4 < 1280) { src = Wic; o = (long)n * 512 + (k4 - 768); }
  } else if (g == 1) {
    if (k4 < 256)       { src = Wfx; o = (long)n * 256 + k4; }
    else if (k4 < 768)  { src = Wfh; o = (long)n * 512 + (k4 - 256); }
    else if (k4 < 1280) { src = Wfc; o = (long)n * 512 + (k4 - 768); }
  } else if (g == 2) {
    if (k4 < 256)       { src = Wtx; o = (long)n * 256 + k4; }
  } else if (g == 3) {
    if (k4 < 256)       { src = Wcx; o = (long)n * 256 + k4; }
    else if (k4 < 768)  { src = Wch; o = (long)n * 512 + (k4 - 256); }
  } else if (g == 4) {
    if (k4 < 256)       { src = Wox; o = (long)n * 256 + k4; }
    else if (k4 < 768)  { src = Woh; o = (long)n * 512 + (k4 - 256); }
    else if (k4 < 1280) { src = Woc; o = (long)n * 512 + (k4 - 768); }
    else if (k4 < 1296) { src = Wot; o = (long)n * 16 + (k4 - 1280); }
  } else {
    if (k4 >= 1280 && k4 < 1296) { src = Wtt; o = (long)n * 16 + (k4 - 1280); }
  }
  float4 v = make_float4(0.f, 0.f, 0.f, 0.f);
  if (src) v = *(const float4*)(src + o);
  ushort4 u;
  u.x = f2bf(v.x); u.y = f2bf(v.y); u.z = f2bf(v.z); u.w = f2bf(v.w);
  *(ushort4*)(Wp + idx * 4) = u;
}

// compute one K-block from LDS buffer `base`; compile-time gate MASK
template<unsigned MASK>
__device__ __forceinline__ void comp_kb(const char* lds, int base,
                                        int wr, int wc16, int lrow, int kgrp,
                                        f32x4 acc[6][4]) {
  const int swz = (lrow & 7) << 4;
#pragma unroll
  for (int kf = 0; kf < 2; ++kf) {
    const int koff2 = kf * 64 + kgrp * 16;       // byte offset of this lane's K-slice
    bf16x8 a[4];
#pragma unroll
    for (int i = 0; i < 4; ++i) {
      const int ar = wr + lrow + 16 * i;
      a[i] = *(const bf16x8*)(lds + base + ar * 128 + (koff2 ^ swz));
    }
#pragma unroll
    for (int g = 0; g < 6; ++g) {
      if (MASK & (1u << g)) {
        const int col = wc16 + lrow;
        bf16x8 b = *(const bf16x8*)(lds + base + WOFF + g * 4096 + col * 128 + (koff2 ^ swz));
#pragma unroll
        for (int i = 0; i < 4; ++i)
          acc[g][i] = __builtin_amdgcn_mfma_f32_16x16x32_bf16(a[i], b, acc[g][i], 0, 0, 0);
      }
    }
  }
}

// stage K-block kb into LDS buffer `base` (runtime mask: wave-uniform branches only)
__device__ __forceinline__ void stage_kb(char* lds, int base, int kb, unsigned mask,
                                         const char* abase, const char* wbase, int wid) {
  const unsigned kbyte = (unsigned)kb * 128u;
  // A: this wave stages rows [wid*32, wid*32+32)
#pragma unroll
  for (int j = 0; j < 4; ++j)
    gld16(abase + (kbyte + (unsigned)j * (8u * KPB)), lds + base + wid * 4096 + j * 1024);
  // W: this wave stages cols [wid*8, wid*8+8) of each active gate
#pragma unroll
  for (int g = 0; g < 6; ++g)
    if (mask & (1u << g))
      gld16(wbase + (kbyte + (unsigned)g * (512u * KPB)),
            lds + base + WOFF + g * 4096 + wid * 1024);
}

// ---------------- main fused kernel ----------------
__global__ __launch_bounds__(256, 2) void lstm_main(
    const unsigned short* __restrict__ Ap, const unsigned short* __restrict__ Wp,
    const float* __restrict__ c_prev,
    const float* __restrict__ b_ix, const float* __restrict__ b_fx,
    const float* __restrict__ b_tx, const float* __restrict__ b_cx,
    const float* __restrict__ b_ox,
    float* __restrict__ out)
{
  __shared__ __align__(16) char lds[2 * BUFSZ];   // 81920 B -> exactly 2 wgs/CU

  const int tid  = threadIdx.x;
  const int lane = tid & 63;
  const int wid  = tid >> 6;

  // bijective XCD swizzle: 2048 wgs; XCD k -> col-blocks [2k, 2k+2) (W slice ~1MB, L2-resident)
  const int bid = blockIdx.x;
  const int swzb = (bid & 7) * 256 + (bid >> 3);
  const int rb = swzb & 127;                 // row block (0..127)
  const int cb = swzb >> 7;                  // col block (0..15)
  const unsigned brow = (unsigned)rb * 128u;
  const int bcol = cb * 32;

  const int wr   = (wid >> 1) * 64;          // wave rows [wr, wr+64)
  const int wc16 = (wid & 1) * 16;           // wave cols [wc16, wc16+16)
  const int lrow = lane & 15;
  const int kgrp = lane >> 4;

  f32x4 acc[6][4];
  {
    f32x4 z = {0.f, 0.f, 0.f, 0.f};
#pragma unroll
    for (int g = 0; g < 6; ++g)
#pragma unroll
      for (int i = 0; i < 4; ++i) acc[g][i] = z;
  }

  // pre-swizzled per-lane source byte offset within a 1KB (8-row) chunk
  const unsigned sb = (unsigned)(((lane & 7) ^ (lane >> 3)) << 4);
  const char* abase = (const char*)Ap +
      ((unsigned long)(brow + wid * 32 + (lane >> 3)) * KPB + sb);
  const char* wbase = (const char*)Wp +
      ((unsigned long)(bcol + wid * 8 + (lane >> 3)) * KPB + sb);

  int curb = 0;
  // prologue
  stage_kb(lds, 0, 0, 0x1Fu, abase, wbase, wid);
  __syncthreads();

#pragma unroll 1
  for (int kb = 0; kb < 3; ++kb) {
    stage_kb(lds, (curb ^ 1) * BUFSZ, kb + 1, 0x1Fu, abase, wbase, wid);
    comp_kb<0x1F>(lds, curb * BUFSZ, wr, wc16, lrow, kgrp, acc);
    __syncthreads(); curb ^= 1;
  }
  { stage_kb(lds, (curb ^ 1) * BUFSZ, 4, 0x1Bu, abase, wbase, wid);
    comp_kb<0x1F>(lds, curb * BUFSZ, wr, wc16, lrow, kgrp, acc);
    __syncthreads(); curb ^= 1; }
#pragma unroll 1
  for (int kb = 4; kb < 11; ++kb) {
    stage_kb(lds, (curb ^ 1) * BUFSZ, kb + 1, 0x1Bu, abase, wbase, wid);
    comp_kb<0x1B>(lds, curb * BUFSZ, wr, wc16, lrow, kgrp, acc);
    __syncthreads(); curb ^= 1;
  }
  { stage_kb(lds, (curb ^ 1) * BUFSZ, 12, 0x13u, abase, wbase, wid);
    comp_kb<0x1B>(lds, curb * BUFSZ, wr, wc16, lrow, kgrp, acc);
    __syncthreads(); curb ^= 1; }
#pragma unroll 1
  for (int kb = 12; kb < 19; ++kb) {
    stage_kb(lds, (curb ^ 1) * BUFSZ, kb + 1, 0x13u, abase, wbase, wid);
    comp_kb<0x13>(lds, curb * BUFSZ, wr, wc16, lrow, kgrp, acc);
    __syncthreads(); curb ^= 1;
  }
  { stage_kb(lds, (curb ^ 1) * BUFSZ, 20, 0x30u, abase, wbase, wid);
    comp_kb<0x13>(lds, curb * BUFSZ, wr, wc16, lrow, kgrp, acc);
    __syncthreads(); curb ^= 1; }
  comp_kb<0x30>(lds, curb * BUFSZ, wr, wc16, lrow, kgrp, acc);

  // ---------------- fused epilogue ----------------
  const int n = bcol + wc16 + lrow;
  const float bi  = b_ix[n], bff = b_fx[n], bt = b_tx[n], bc = b_cx[n], bo = b_ox[n];
  const int rbase = kgrp * 4;
#pragma unroll
  for (int i = 0; i < 4; ++i) {
#pragma unroll
    for (int r = 0; r < 4; ++r) {
      const long m   = (long)brow + wr + 16 * i + rbase + r;
      const long off = m * H_SZ + n;
      const float iv = sigm(acc[0][i][r] + bi);
      const float fv = sigm(acc[1][i][r] + bff);
      const float Tv = sigm(acc[2][i][r] + bt + sigm(acc[5][i][r]));
      const float kv = tanhx(acc[3][i][r] + bc);
      const float ov = sigm(acc[4][i][r] + bo);
      const float cp = c_prev[off];
      const float cn = iv * Tv * kv + fv * cp;
      out[off]          = ov * tanhx(cn);
      out[BH + off]     = cn;
      out[2 * BH + off] = Tv;
    }
  }
}

extern "C" void kernel_launch(void* const* d_in, const int* in_sizes, int n_in,
                              void* d_out, int out_size, void* d_ws, size_t ws_size,
                              hipStream_t stream) {
  const float* x      = (const float*)d_in[0];
  const float* h      = (const float*)d_in[1];
  const float* c_prev = (const float*)d_in[2];
  const float* dl     = (const float*)d_in[3];
  const float* W_ix = (const float*)d_in[4];
  const float* b_ix = (const float*)d_in[5];
  const float* W_ih = (const float*)d_in[6];
  const float* W_ic = (const float*)d_in[7];
  const float* W_fx = (const float*)d_in[8];
  const float* b_fx = (const float*)d_in[9];
  const float* W_fh = (const float*)d_in[10];
  const float* W_fc = (const float*)d_in[11];
  const float* W_tx = (const float*)d_in[12];
  const float* b_tx = (const float*)d_in[13];
  const float* W_tt = (const float*)d_in[14];
  const float* W_cx = (const float*)d_in[15];
  const float* b_cx = (const float*)d_in[16];
  const float* W_ch = (const float*)d_in[17];
  const float* W_ox = (const float*)d_in[18];
  const float* b_ox = (const float*)d_in[19];
  const float* W_oh = (const float*)d_in[20];
  const float* W_oc = (const float*)d_in[21];
  const float* W_ot = (const float*)d_in[22];

  unsigned short* Ap = (unsigned short*)d_ws;                                   // 44.04 MB
  unsigned short* Wp = (unsigned short*)((char*)d_ws + (size_t)B_SZ * KP * 2);  // +8.26 MB

  const long na4 = (long)B_SZ * KP / 4;
  prep_a_kernel<<<(int)((na4 + 255) / 256), 256, 0, stream>>>(x, h, c_prev, dl, Ap);
  const long nw4 = 6L * H_SZ * KP / 4;
  prep_w_kernel<<<(int)((nw4 + 255) / 256), 256, 0, stream>>>(
      W_ix, W_ih, W_ic, W_fx, W_fh, W_fc, W_tx, W_tt, W_cx, W_ch,
      W_ox, W_oh, W_oc, W_ot, Wp);

  lstm_main<<<2048, 256, 0, stream>>>(Ap, Wp, c_prev, b_ix, b_fx, b_tx, b_cx, b_ox,
                                      (float*)d_out);
}